// Round 19
// baseline (168.703 us; speedup 1.0000x reference)
//
#include <hip/hip_runtime.h>
#include <hip/hip_bf16.h>
#include <math.h>

#define N_NODES 50000
#define NPAD 50048                      // 391 * 128
#define N_EDGES 800000
#define NEG_SLOPE 0.2f
#define NBUCK ((N_NODES + 127) / 128)   // 391 buckets of 128 dsts
#define CCHUNK 2048
#define DCAP 4096                       // mean bucket size ~2046, 40+ sigma margin

__device__ inline float lrelu(float x) { return fmaxf(x, NEG_SLOPE * x); }

__device__ inline unsigned bf16rne(float f) {
    unsigned u = __float_as_uint(f);
    return (u + 0x7fffu + ((u >> 16) & 1u)) >> 16;
}
__device__ inline float bf2f(unsigned h) { return __uint_as_float(h << 16); }

// ---------------- CSR build pieces ----------------
__device__ __forceinline__ void count_body(int bx, const int* __restrict__ ei,
                                           int* __restrict__ gbcnt) {
    __shared__ int lc[NBUCK];
    for (int i = threadIdx.x; i < NBUCK; i += 256) lc[i] = 0;
    __syncthreads();
    for (int e = bx * 256 + threadIdx.x; e < N_EDGES; e += 256 * 256)
        atomicAdd(&lc[ei[N_EDGES + e] >> 7], 1);
    __syncthreads();
    for (int i = threadIdx.x; i < NBUCK; i += 256)
        if (lc[i]) atomicAdd(&gbcnt[i], lc[i]);
}

// blocks 0..127: W1/W2 transpose+bf16 split; blocks 128..383: bucket histogram
__global__ __launch_bounds__(256) void convw_count_kernel(const float* __restrict__ W1,
                                                          unsigned short* __restrict__ w1h,
                                                          unsigned short* __restrict__ w1l,
                                                          const float* __restrict__ W2,
                                                          unsigned short* __restrict__ w2h,
                                                          unsigned short* __restrict__ w2l,
                                                          const int* __restrict__ ei,
                                                          int* __restrict__ gbcnt) {
    int b = blockIdx.x;
    int t = threadIdx.x;
    if (b < 128) {
        int idx = b * 256 + t;
        const float* W = W1;
        unsigned short* th = w1h;
        unsigned short* tl = w1l;
        if (idx >= 128 * 128) { W = W2; th = w2h; tl = w2l; idx -= 128 * 128; }
        int c = idx >> 7, k = idx & 127;
        float v = W[(size_t)k * 128 + c];
        unsigned h = bf16rne(v);
        th[idx] = (unsigned short)h;
        tl[idx] = (unsigned short)bf16rne(v - bf2f(h));
    } else {
        count_body(b - 128, ei, gbcnt);
    }
}

// pk = src | (dst<<16); bucket = pk>>23 (dst>>7); dst_low = (pk>>16)&127
__global__ __launch_bounds__(256) void bucketscatter_kernel(const int* __restrict__ ei,
                                                            int* __restrict__ bcur,
                                                            unsigned* __restrict__ bpairs) {
    __shared__ int cnt[NBUCK], startl[NBUCK], baseg[NBUCK], cur2[NBUCK];
    __shared__ int ss[256];
    __shared__ unsigned stage[CCHUNK];
    int t = threadIdx.x;
    int e0 = blockIdx.x * CCHUNK;
    int nume = min(CCHUNK, N_EDGES - e0);
    for (int i = t; i < NBUCK; i += 256) { cnt[i] = 0; cur2[i] = 0; }
    __syncthreads();
    int src[CCHUNK / 256], dst[CCHUNK / 256];
    #pragma unroll
    for (int j = 0; j < CCHUNK / 256; ++j) {
        int idx = t + j * 256;
        if (idx < nume) {
            src[j] = ei[e0 + idx];
            dst[j] = ei[N_EDGES + e0 + idx];
            atomicAdd(&cnt[dst[j] >> 7], 1);
        } else dst[j] = -1;
    }
    __syncthreads();
    {   // exclusive scan of cnt[NBUCK] (2 values per thread)
        int i0 = 2 * t, i1 = 2 * t + 1;
        int a = (i0 < NBUCK) ? cnt[i0] : 0;
        int bv = (i1 < NBUCK) ? cnt[i1] : 0;
        int s = a + bv;
        ss[t] = s;
        __syncthreads();
        for (int d = 1; d < 256; d <<= 1) {
            int u = (t >= d) ? ss[t - d] : 0;
            __syncthreads();
            ss[t] += u;
            __syncthreads();
        }
        int excl = ss[t] - s;
        if (i0 < NBUCK) startl[i0] = excl;
        if (i1 < NBUCK) startl[i1] = excl + a;
    }
    __syncthreads();
    for (int i = t; i < NBUCK; i += 256)
        if (cnt[i] > 0) baseg[i] = atomicAdd(&bcur[i], cnt[i]);
    __syncthreads();
    #pragma unroll
    for (int j = 0; j < CCHUNK / 256; ++j) {
        if (dst[j] >= 0) {
            int b = dst[j] >> 7;
            int slot = startl[b] + atomicAdd(&cur2[b], 1);
            stage[slot] = (unsigned)src[j] | ((unsigned)dst[j] << 16);
        }
    }
    __syncthreads();
    for (int i = t; i < nume; i += 256) {
        unsigned pk = stage[i];
        int b = pk >> 23;
        bpairs[baseg[b] + (i - startl[b])] = pk;
    }
}

__global__ __launch_bounds__(256) void csrfinalize_kernel(const unsigned* __restrict__ bpairs,
                                                          const int* __restrict__ bbase,
                                                          int* __restrict__ ptr,
                                                          unsigned short* __restrict__ csr) {
    __shared__ int cnt[128], excl[128], cur[128];
    __shared__ int ss[128];
    __shared__ unsigned P[DCAP];
    int b = blockIdx.x, t = threadIdx.x;
    int bb = bbase[b], be = bbase[b + 1];
    int n = be - bb;
    int d0 = b << 7;
    int dmax = min(128, N_NODES - d0);
    bool fits = (n <= DCAP);
    if (t < 128) { cnt[t] = 0; cur[t] = 0; }
    __syncthreads();
    for (int i = t; i < n; i += 256) {
        unsigned pk = bpairs[bb + i];
        if (fits) P[i] = pk;
        atomicAdd(&cnt[(pk >> 16) & 127], 1);
    }
    __syncthreads();
    if (t < 128) {   // exclusive scan of cnt[128]
        int v = cnt[t];
        ss[t] = v;
        __syncthreads();
        for (int d = 1; d < 128; d <<= 1) {
            int u = (t >= d) ? ss[t - d] : 0;
            __syncthreads();
            ss[t] += u;
            __syncthreads();
        }
        excl[t] = ss[t] - v;
    } else {
        // keep barrier counts matched across the block (7 iterations + 1)
        __syncthreads();
        for (int d = 1; d < 128; d <<= 1) { __syncthreads(); __syncthreads(); }
    }
    __syncthreads();
    if (t < dmax) ptr[d0 + t] = bb + excl[t];
    if (b == NBUCK - 1 && t == 0) ptr[N_NODES] = N_EDGES;
    for (int i = t; i < n; i += 256) {
        unsigned pk = fits ? P[i] : bpairs[bb + i];
        int ld = (pk >> 16) & 127;
        int pos = bb + excl[ld] + atomicAdd(&cur[ld], 1);
        csr[pos] = (unsigned short)(pk & 0xFFFFu);
    }
}

// ---- MFMA GEMM body (bf16x2 split) + attention-logit epilogue ----
template <int H, int AF32>
__device__ __forceinline__ void gemm_body(int bx,
                                          const unsigned short* __restrict__ Ah,
                                          const unsigned short* __restrict__ Al,
                                          const float* __restrict__ Af,
                                          const unsigned short* __restrict__ Bh,
                                          const unsigned short* __restrict__ Bl,
                                          const float* __restrict__ asrc,
                                          const float* __restrict__ adst,
                                          unsigned short* __restrict__ Hb,
                                          float* __restrict__ als,
                                          float* __restrict__ ald,
                                          int nrows) {
    using bf16x8 = __attribute__((ext_vector_type(8))) short;
    using f32x4  = __attribute__((ext_vector_type(4))) float;
    const int lane = threadIdx.x & 63;
    const int wv = threadIdx.x >> 6;
    const int l15 = lane & 15;
    const int g = lane >> 4;
    const int lk = g * 8;
    const int rowbase = bx * 128 + wv * 32;
    const int r0c = min(rowbase + l15, nrows - 1);
    const int r1c = min(rowbase + 16 + l15, nrows - 1);

    f32x4 acc[2][8];
    #pragma unroll
    for (int rt = 0; rt < 2; ++rt)
        #pragma unroll
        for (int ct = 0; ct < 8; ++ct) acc[rt][ct] = (f32x4){0.f, 0.f, 0.f, 0.f};

    #pragma unroll
    for (int kc = 0; kc < 4; ++kc) {
        const int ko = kc * 32 + lk;
        bf16x8 ah0, ah1, al0, al1;
        if constexpr (AF32) {
            const float* b0 = Af + (size_t)r0c * 128 + ko;
            const float* b1 = Af + (size_t)r1c * 128 + ko;
            float4 u0 = *(const float4*)b0, u1 = *(const float4*)(b0 + 4);
            float4 v0 = *(const float4*)b1, v1 = *(const float4*)(b1 + 4);
            float a0[8] = {u0.x, u0.y, u0.z, u0.w, u1.x, u1.y, u1.z, u1.w};
            float a1[8] = {v0.x, v0.y, v0.z, v0.w, v1.x, v1.y, v1.z, v1.w};
            #pragma unroll
            for (int i = 0; i < 8; ++i) {
                unsigned h0 = bf16rne(a0[i]);
                ah0[i] = (short)h0; al0[i] = (short)bf16rne(a0[i] - bf2f(h0));
                unsigned h1 = bf16rne(a1[i]);
                ah1[i] = (short)h1; al1[i] = (short)bf16rne(a1[i] - bf2f(h1));
            }
        } else {
            ah0 = *(const bf16x8*)(Ah + (size_t)(rowbase + l15) * 128 + ko);
            ah1 = *(const bf16x8*)(Ah + (size_t)(rowbase + 16 + l15) * 128 + ko);
            al0 = *(const bf16x8*)(Al + (size_t)(rowbase + l15) * 128 + ko);
            al1 = *(const bf16x8*)(Al + (size_t)(rowbase + 16 + l15) * 128 + ko);
        }
        #pragma unroll
        for (int ct = 0; ct < 8; ++ct) {
            bf16x8 bh = *(const bf16x8*)(Bh + (size_t)(ct * 16 + l15) * 128 + ko);
            bf16x8 bl = *(const bf16x8*)(Bl + (size_t)(ct * 16 + l15) * 128 + ko);
            acc[0][ct] = __builtin_amdgcn_mfma_f32_16x16x32_bf16(ah0, bh, acc[0][ct], 0, 0, 0);
            acc[0][ct] = __builtin_amdgcn_mfma_f32_16x16x32_bf16(ah0, bl, acc[0][ct], 0, 0, 0);
            acc[0][ct] = __builtin_amdgcn_mfma_f32_16x16x32_bf16(al0, bh, acc[0][ct], 0, 0, 0);
            acc[1][ct] = __builtin_amdgcn_mfma_f32_16x16x32_bf16(ah1, bh, acc[1][ct], 0, 0, 0);
            acc[1][ct] = __builtin_amdgcn_mfma_f32_16x16x32_bf16(ah1, bl, acc[1][ct], 0, 0, 0);
            acc[1][ct] = __builtin_amdgcn_mfma_f32_16x16x32_bf16(al1, bh, acc[1][ct], 0, 0, 0);
        }
    }

    float as8[8], ad8[8];
    #pragma unroll
    for (int ct = 0; ct < 8; ++ct) { as8[ct] = asrc[ct * 16 + l15]; ad8[ct] = adst[ct * 16 + l15]; }

    #pragma unroll
    for (int rt = 0; rt < 2; ++rt) {
        #pragma unroll
        for (int ct = 0; ct < 8; ++ct) {
            #pragma unroll
            for (int j = 0; j < 4; ++j) {
                int row = rowbase + rt * 16 + g * 4 + j;
                if (row < nrows)
                    Hb[(size_t)row * 128 + ct * 16 + l15] = (unsigned short)bf16rne(acc[rt][ct][j]);
            }
        }
        #pragma unroll
        for (int j = 0; j < 4; ++j) {
            int row = rowbase + rt * 16 + g * 4 + j;
            if (H == 2) {
                float sp0 = 0.f, sp1 = 0.f, dp0 = 0.f, dp1 = 0.f;
                #pragma unroll
                for (int ct = 0; ct < 4; ++ct) { sp0 += acc[rt][ct][j] * as8[ct]; dp0 += acc[rt][ct][j] * ad8[ct]; }
                #pragma unroll
                for (int ct = 4; ct < 8; ++ct) { sp1 += acc[rt][ct][j] * as8[ct]; dp1 += acc[rt][ct][j] * ad8[ct]; }
                #pragma unroll
                for (int off = 1; off < 16; off <<= 1) {
                    sp0 += __shfl_xor(sp0, off); sp1 += __shfl_xor(sp1, off);
                    dp0 += __shfl_xor(dp0, off); dp1 += __shfl_xor(dp1, off);
                }
                if (l15 == 0 && row < nrows) {
                    als[(size_t)row * 2]     = sp0; als[(size_t)row * 2 + 1] = sp1;
                    ald[(size_t)row * 2]     = dp0; ald[(size_t)row * 2 + 1] = dp1;
                }
            } else {
                float sp = 0.f, dp = 0.f;
                #pragma unroll
                for (int ct = 0; ct < 8; ++ct) { sp += acc[rt][ct][j] * as8[ct]; dp += acc[rt][ct][j] * ad8[ct]; }
                #pragma unroll
                for (int off = 1; off < 16; off <<= 1) {
                    sp += __shfl_xor(sp, off); dp += __shfl_xor(dp, off);
                }
                if (l15 == 0 && row < nrows) { als[row] = sp; ald[row] = dp; }
            }
        }
    }
}

template <int H, int AF32>
__global__ __launch_bounds__(256) void gemm_mfma_kernel(const unsigned short* __restrict__ Ah,
                                                        const unsigned short* __restrict__ Al,
                                                        const float* __restrict__ Af,
                                                        const unsigned short* __restrict__ Bh,
                                                        const unsigned short* __restrict__ Bl,
                                                        const float* __restrict__ asrc,
                                                        const float* __restrict__ adst,
                                                        unsigned short* __restrict__ Hb,
                                                        float* __restrict__ als,
                                                        float* __restrict__ ald,
                                                        int nrows) {
    gemm_body<H, AF32>(blockIdx.x, Ah, Al, Af, Bh, Bl, asrc, adst, Hb, als, ald, nrows);
}

// fused: layer-1 GEMM (blocks 0..gemmblocks-1) + bucket scan (last block)
template <int H, int AF32>
__global__ __launch_bounds__(256) void gemm_scan_kernel(const float* __restrict__ Af,
                                                        const unsigned short* __restrict__ Bh,
                                                        const unsigned short* __restrict__ Bl,
                                                        const float* __restrict__ asrc,
                                                        const float* __restrict__ adst,
                                                        unsigned short* __restrict__ Hb,
                                                        float* __restrict__ als,
                                                        float* __restrict__ ald,
                                                        int nrows,
                                                        const int* __restrict__ gbcnt,
                                                        int* __restrict__ bbase,
                                                        int* __restrict__ bcur,
                                                        int gemmblocks) {
    if ((int)blockIdx.x < gemmblocks) {
        gemm_body<H, AF32>(blockIdx.x, nullptr, nullptr, Af, Bh, Bl, asrc, adst, Hb, als, ald, nrows);
    } else {
        __shared__ int ss[256];
        int t = threadIdx.x;
        int i0 = 2 * t, i1 = 2 * t + 1;
        int a = (i0 < NBUCK) ? gbcnt[i0] : 0;
        int bv = (i1 < NBUCK) ? gbcnt[i1] : 0;
        int s = a + bv;
        ss[t] = s;
        __syncthreads();
        for (int d = 1; d < 256; d <<= 1) {
            int u = (t >= d) ? ss[t - d] : 0;
            __syncthreads();
            ss[t] += u;
            __syncthreads();
        }
        int excl = ss[t] - s;
        if (i0 < NBUCK) { bbase[i0] = excl; bcur[i0] = excl; }
        if (i1 < NBUCK) { bbase[i1] = excl + a; bcur[i1] = excl + a; }
        if (t == 0) bbase[NBUCK] = N_EDGES;
    }
}

// ---- fused softmax+gather v5: 2 dsts per wave (32 lanes each), uint2 gathers ----
template <int H, int DO_ELU, int BSPLIT>
__global__ __launch_bounds__(256) void aggregate_kernel(const unsigned short* __restrict__ Hb,
                                                        const float* __restrict__ als,
                                                        const float* __restrict__ aldv,
                                                        const int* __restrict__ ptr,
                                                        const unsigned short* __restrict__ csr,
                                                        const float* __restrict__ bias,
                                                        float* __restrict__ out,
                                                        unsigned short* __restrict__ oh,
                                                        unsigned short* __restrict__ ol) {
    __shared__ int   s_src[4][2][34];
    __shared__ float s_p[4][2][H][34];
    const uint2*  __restrict__ Hb2  = (const uint2*)Hb;
    const float2* __restrict__ als2 = (const float2*)als;
    const int w = threadIdx.x >> 6;
    const int lane = threadIdx.x & 63;
    const int half = lane >> 5;
    const int l31 = lane & 31;
    const int headc = (H == 2) ? (l31 >> 4) : 0;

    int d = blockIdx.x * 8 + w * 2 + half;
    bool valid = d < N_NODES;
    int dv = valid ? d : N_NODES - 1;
    int beg = ptr[dv];
    int end = valid ? ptr[dv + 1] : beg;

    float ald0, ald1 = 0.f, es0, es1 = 0.f;
    if (H == 2) {
        float2 ta = ((const float2*)aldv)[(unsigned)dv];
        float2 ts = als2[(unsigned)dv];
        ald0 = ta.x; ald1 = ta.y;
        es0 = lrelu(ts.x + ald0); es1 = lrelu(ts.y + ald1);
    } else {
        ald0 = aldv[dv]; es0 = lrelu(als[dv] + ald0);
    }

    int k0 = beg + l31;
    int src0 = dv;
    float e0 = -INFINITY, e1 = -INFINITY;
    if (k0 < end) {
        src0 = csr[k0];
        if (H == 2) {
            float2 t = als2[(unsigned)src0];
            e0 = lrelu(t.x + ald0); e1 = lrelu(t.y + ald1);
        } else e0 = lrelu(als[(unsigned)src0] + ald0);
    }
    float m0 = fmaxf(es0, e0);
    float m1 = (H == 2) ? fmaxf(es1, e1) : 0.f;
    for (int k = k0 + 32; k < end; k += 32) {
        int s = csr[k];
        if (H == 2) {
            float2 t = als2[(unsigned)s];
            m0 = fmaxf(m0, lrelu(t.x + ald0));
            m1 = fmaxf(m1, lrelu(t.y + ald1));
        } else m0 = fmaxf(m0, lrelu(als[(unsigned)s] + ald0));
    }
    #pragma unroll
    for (int off = 16; off; off >>= 1) {
        m0 = fmaxf(m0, __shfl_xor(m0, off));
        if (H == 2) m1 = fmaxf(m1, __shfl_xor(m1, off));
    }

    float l0 = 0.f, l1 = 0.f;
    float ac0[4], ac1[4], ac2[4], ac3[4];
    #pragma unroll
    for (int i = 0; i < 4; ++i) { ac0[i] = 0.f; ac1[i] = 0.f; ac2[i] = 0.f; ac3[i] = 0.f; }

    for (int tt = 0; ; ++tt) {
        int t0 = beg + tt * 32;
        int degT = end - t0;
        degT = degT < 0 ? 0 : (degT > 32 ? 32 : degT);
        int jm = max(degT, __shfl_xor(degT, 32));
        if (jm == 0) break;
        {
            int k = t0 + l31;
            int s = dv;
            float p0v = 0.f, p1v = 0.f;
            if (k < end) {
                float f0, f1 = 0.f;
                if (tt == 0) { s = src0; f0 = e0; f1 = e1; }
                else {
                    s = csr[k];
                    if (H == 2) {
                        float2 t = als2[(unsigned)s];
                        f0 = lrelu(t.x + ald0); f1 = lrelu(t.y + ald1);
                    } else f0 = lrelu(als[(unsigned)s] + ald0);
                }
                p0v = __expf(f0 - m0);
                l0 += p0v;
                if (H == 2) { p1v = __expf(f1 - m1); l1 += p1v; }
            }
            s_src[w][half][l31] = s;
            s_p[w][half][0][l31] = p0v;
            if (H == 2) s_p[w][half][1][l31] = p1v;
        }
        int j = 0;
        for (; j + 3 < jm; j += 4) {
            int sA = s_src[w][half][j],     sB = s_src[w][half][j + 1];
            int sC = s_src[w][half][j + 2], sD = s_src[w][half][j + 3];
            float pA = s_p[w][half][headc][j],     pB = s_p[w][half][headc][j + 1];
            float pC = s_p[w][half][headc][j + 2], pD = s_p[w][half][headc][j + 3];
            uint2 uA = Hb2[((unsigned)sA << 5) + l31];
            uint2 uB = Hb2[((unsigned)sB << 5) + l31];
            uint2 uC = Hb2[((unsigned)sC << 5) + l31];
            uint2 uD = Hb2[((unsigned)sD << 5) + l31];
            ac0[0] = fmaf(pA, __uint_as_float(uA.x << 16), ac0[0]);
            ac0[1] = fmaf(pA, __uint_as_float(uA.x & 0xffff0000u), ac0[1]);
            ac0[2] = fmaf(pA, __uint_as_float(uA.y << 16), ac0[2]);
            ac0[3] = fmaf(pA, __uint_as_float(uA.y & 0xffff0000u), ac0[3]);
            ac1[0] = fmaf(pB, __uint_as_float(uB.x << 16), ac1[0]);
            ac1[1] = fmaf(pB, __uint_as_float(uB.x & 0xffff0000u), ac1[1]);
            ac1[2] = fmaf(pB, __uint_as_float(uB.y << 16), ac1[2]);
            ac1[3] = fmaf(pB, __uint_as_float(uB.y & 0xffff0000u), ac1[3]);
            ac2[0] = fmaf(pC, __uint_as_float(uC.x << 16), ac2[0]);
            ac2[1] = fmaf(pC, __uint_as_float(uC.x & 0xffff0000u), ac2[1]);
            ac2[2] = fmaf(pC, __uint_as_float(uC.y << 16), ac2[2]);
            ac2[3] = fmaf(pC, __uint_as_float(uC.y & 0xffff0000u), ac2[3]);
            ac3[0] = fmaf(pD, __uint_as_float(uD.x << 16), ac3[0]);
            ac3[1] = fmaf(pD, __uint_as_float(uD.x & 0xffff0000u), ac3[1]);
            ac3[2] = fmaf(pD, __uint_as_float(uD.y << 16), ac3[2]);
            ac3[3] = fmaf(pD, __uint_as_float(uD.y & 0xffff0000u), ac3[3]);
        }
        for (; j < jm; ++j) {
            int sA = s_src[w][half][j];
            float pA = s_p[w][half][headc][j];
            uint2 uA = Hb2[((unsigned)sA << 5) + l31];
            ac0[0] = fmaf(pA, __uint_as_float(uA.x << 16), ac0[0]);
            ac0[1] = fmaf(pA, __uint_as_float(uA.x & 0xffff0000u), ac0[1]);
            ac0[2] = fmaf(pA, __uint_as_float(uA.y << 16), ac0[2]);
            ac0[3] = fmaf(pA, __uint_as_float(uA.y & 0xffff0000u), ac0[3]);
        }
    }

    float acc[4];
    #pragma unroll
    for (int i = 0; i < 4; ++i) acc[i] = (ac0[i] + ac1[i]) + (ac2[i] + ac3[i]);

    float mh  = (headc == 0) ? m0 : m1;
    float esh = (headc == 0) ? es0 : es1;
    float psh = __expf(esh - mh);
    {
        uint2 u = Hb2[((unsigned)dv << 5) + l31];
        acc[0] = fmaf(psh, __uint_as_float(u.x << 16), acc[0]);
        acc[1] = fmaf(psh, __uint_as_float(u.x & 0xffff0000u), acc[1]);
        acc[2] = fmaf(psh, __uint_as_float(u.y << 16), acc[2]);
        acc[3] = fmaf(psh, __uint_as_float(u.y & 0xffff0000u), acc[3]);
    }
    #pragma unroll
    for (int off = 16; off; off >>= 1) {
        l0 += __shfl_xor(l0, off);
        if (H == 2) l1 += __shfl_xor(l1, off);
    }
    float denom = ((headc == 0) ? l0 : l1) + psh;
    float inv = 1.f / (denom + 1e-16f);
    float4 b4 = *(const float4*)(bias + 4 * l31);
    float o0 = acc[0] * inv + b4.x;
    float o1 = acc[1] * inv + b4.y;
    float o2 = acc[2] * inv + b4.z;
    float o3 = acc[3] * inv + b4.w;
    if (DO_ELU) {
        o0 = o0 > 0.f ? o0 : __expf(o0) - 1.f;
        o1 = o1 > 0.f ? o1 : __expf(o1) - 1.f;
        o2 = o2 > 0.f ? o2 : __expf(o2) - 1.f;
        o3 = o3 > 0.f ? o3 : __expf(o3) - 1.f;
    }
    if (valid) {
        if (BSPLIT) {
            unsigned h0 = bf16rne(o0), h1 = bf16rne(o1), h2 = bf16rne(o2), h3 = bf16rne(o3);
            ushort4 sh; sh.x = h0; sh.y = h1; sh.z = h2; sh.w = h3;
            ushort4 sl;
            sl.x = bf16rne(o0 - bf2f(h0)); sl.y = bf16rne(o1 - bf2f(h1));
            sl.z = bf16rne(o2 - bf2f(h2)); sl.w = bf16rne(o3 - bf2f(h3));
            *(ushort4*)(oh + (size_t)dv * 128 + 4 * l31) = sh;
            *(ushort4*)(ol + (size_t)dv * 128 + 4 * l31) = sl;
        } else {
            *(float4*)(out + (size_t)dv * 128 + 4 * l31) = make_float4(o0, o1, o2, o3);
        }
    }
}

// ---------------- launch ----------------
extern "C" void kernel_launch(void* const* d_in, const int* in_sizes, int n_in,
                              void* d_out, int out_size, void* d_ws, size_t ws_size,
                              hipStream_t stream) {
    const float* x      = (const float*)d_in[0];
    const int*   ei     = (const int*)d_in[1];
    const float* W1     = (const float*)d_in[2];
    const float* a_src1 = (const float*)d_in[3];
    const float* a_dst1 = (const float*)d_in[4];
    const float* b1     = (const float*)d_in[5];
    const float* W2     = (const float*)d_in[6];
    const float* a_src2 = (const float*)d_in[7];
    const float* a_dst2 = (const float*)d_in[8];
    const float* b2     = (const float*)d_in[9];
    float* out = (float*)d_out;

    char* ws = (char*)d_ws;
    size_t off = 0;
    auto alloc = [&](size_t bytes) { void* p = ws + off; off += (bytes + 255) & ~(size_t)255; return p; };
    int*      ptr    = (int*)alloc((N_NODES + 1) * sizeof(int));
    int*      gbcnt  = (int*)alloc(NBUCK * sizeof(int));
    int*      bbase  = (int*)alloc((NBUCK + 1) * sizeof(int));
    int*      bcur   = (int*)alloc(NBUCK * sizeof(int));
    unsigned* bpairs = (unsigned*)alloc((size_t)N_EDGES * sizeof(unsigned));
    unsigned short* csr = (unsigned short*)alloc((size_t)N_EDGES * sizeof(unsigned short));
    unsigned short* x2h = (unsigned short*)alloc((size_t)NPAD * 128 * 2);
    unsigned short* x2l = (unsigned short*)alloc((size_t)NPAD * 128 * 2);
    unsigned short* hb  = (unsigned short*)alloc((size_t)N_NODES * 128 * 2);
    unsigned short* w1h = (unsigned short*)alloc(128 * 128 * 2);
    unsigned short* w1l = (unsigned short*)alloc(128 * 128 * 2);
    unsigned short* w2h = (unsigned short*)alloc(128 * 128 * 2);
    unsigned short* w2l = (unsigned short*)alloc(128 * 128 * 2);
    float* als    = (float*)alloc(N_NODES * 2 * sizeof(float));
    float* ald    = (float*)alloc(N_NODES * 2 * sizeof(float));

    int gblocks = NPAD / 128;             // 391
    int wblocks = (N_NODES + 7) / 8;

    hipMemsetAsync(gbcnt, 0, NBUCK * sizeof(int), stream);
    convw_count_kernel<<<128 + 256, 256, 0, stream>>>(W1, w1h, w1l, W2, w2h, w2l, ei, gbcnt);
    gemm_scan_kernel<2, 1><<<gblocks + 1, 256, 0, stream>>>(x, w1h, w1l, a_src1, a_dst1,
                                                            hb, als, ald, N_NODES,
                                                            gbcnt, bbase, bcur, gblocks);
    bucketscatter_kernel<<<(N_EDGES + CCHUNK - 1) / CCHUNK, 256, 0, stream>>>(ei, bcur, bpairs);
    csrfinalize_kernel<<<NBUCK, 256, 0, stream>>>(bpairs, bbase, ptr, csr);

    aggregate_kernel<2, 1, 1><<<wblocks, 256, 0, stream>>>(hb, als, ald, ptr, csr, b1,
                                                           nullptr, x2h, x2l);
    gemm_mfma_kernel<1, 0><<<gblocks, 256, 0, stream>>>(x2h, x2l, nullptr, w2h, w2l,
                                                        a_src2, a_dst2, hb, als, ald, N_NODES);
    aggregate_kernel<1, 0, 0><<<wblocks, 256, 0, stream>>>(hb, als, ald, ptr, csr, b2,
                                                           out, nullptr, nullptr);
}